// Round 5
// baseline (50.866 us; speedup 1.0000x reference)
//
#include <hip/hip_runtime.h>

// NeRF volume rendering. R4: 16 samples per lane, 8 lanes per ray, 8 rays/wave.
// Fewer cross-lane (DS-pipe) ops per ray: 6 cross passes x 16 regs / 8 rays
// = 12 DS/ray (vs 20 at 8-per-lane). All CEs uniform-ascending via the
// reversal formulation. Plain (cached) stores — NT stores regressed in R3.

#define CEX(a,b) { float mn_=fminf(v[a],v[b]); v[b]=fmaxf(v[a],v[b]); v[a]=mn_; }

// Batcher odd-even mergesort of 8 ascending on regs base..base+7 (19 CEs)
#define SORT8(B) \
  CEX(B+0,B+1) CEX(B+2,B+3) CEX(B+4,B+5) CEX(B+6,B+7) \
  CEX(B+0,B+2) CEX(B+1,B+3) CEX(B+4,B+6) CEX(B+5,B+7) \
  CEX(B+1,B+2) CEX(B+5,B+6) \
  CEX(B+0,B+4) CEX(B+1,B+5) CEX(B+2,B+6) CEX(B+3,B+7) \
  CEX(B+2,B+4) CEX(B+3,B+5) \
  CEX(B+1,B+2) CEX(B+3,B+4) CEX(B+5,B+6)

// bitonic merge of 8 (strides 4,2,1) on regs base..base+7 (12 CEs)
#define MERGE8(B) \
  CEX(B+0,B+4) CEX(B+1,B+5) CEX(B+2,B+6) CEX(B+3,B+7) \
  CEX(B+0,B+2) CEX(B+1,B+3) CEX(B+4,B+6) CEX(B+5,B+7) \
  CEX(B+0,B+1) CEX(B+2,B+3) CEX(B+4,B+5) CEX(B+6,B+7)

// in-lane merge of two sorted 8-seqs -> sorted 16 (reversal + 2x merge8)
#define MERGE16_FROM_8 \
  CEX(0,15) CEX(1,14) CEX(2,13) CEX(3,12) CEX(4,11) CEX(5,10) CEX(6,9) CEX(7,8) \
  MERGE8(0) MERGE8(8)

// in-lane bitonic merge of 16 (strides 8,4,2,1; 32 CEs)
#define INLANE16 \
  CEX(0,8) CEX(1,9) CEX(2,10) CEX(3,11) CEX(4,12) CEX(5,13) CEX(6,14) CEX(7,15) \
  CEX(0,4) CEX(1,5) CEX(2,6) CEX(3,7) CEX(8,12) CEX(9,13) CEX(10,14) CEX(11,15) \
  CEX(0,2) CEX(1,3) CEX(4,6) CEX(5,7) CEX(8,10) CEX(9,11) CEX(12,14) CEX(13,15) \
  CEX(0,1) CEX(2,3) CEX(4,5) CEX(6,7) CEX(8,9) CEX(10,11) CEX(12,13) CEX(14,15)

// first pass of a cross-lane merge: partner = reversed regs, lane xor mask
#define CROSS_REV(mask, lowbit) { \
  float w_[16]; \
  _Pragma("unroll") for (int r_=0;r_<16;++r_) w_[r_]=__shfl_xor(v[15-r_], (mask)); \
  const bool lo_ = (gl & (lowbit)) == 0; \
  _Pragma("unroll") for (int r_=0;r_<16;++r_) \
    v[r_] = lo_ ? fminf(v[r_],w_[r_]) : fmaxf(v[r_],w_[r_]); }

// uniform-ascending cross-lane CE pass
#define CROSS(mask, lowbit) { \
  float w_[16]; \
  _Pragma("unroll") for (int r_=0;r_<16;++r_) w_[r_]=__shfl_xor(v[r_], (mask)); \
  const bool lo_ = (gl & (lowbit)) == 0; \
  _Pragma("unroll") for (int r_=0;r_<16;++r_) \
    v[r_] = lo_ ? fminf(v[r_],w_[r_]) : fmaxf(v[r_],w_[r_]); }

__global__ __launch_bounds__(256) void nerf_render_kernel(
    const float* __restrict__ t,
    const float* __restrict__ sigma,
    const float* __restrict__ c,
    float* __restrict__ out,
    int n_rays) {
  const int tid  = threadIdx.x;
  const int lane = tid & 63;
  const int gl   = lane & 7;                // lane within the 8-lane ray group
  const int ray  = blockIdx.x * 32 + (tid >> 3);
  if (ray >= n_rays) return;

  // ---- load t: 16 contiguous samples per lane ----
  const float4* tb = (const float4*)(t + (size_t)ray * 128 + gl * 16);
  float v[16];
#pragma unroll
  for (int q = 0; q < 4; ++q) {
    const float4 a = tb[q];
    v[4*q+0]=a.x; v[4*q+1]=a.y; v[4*q+2]=a.z; v[4*q+3]=a.w;
  }

  // ---- in-lane sort of 16 ----
  SORT8(0) SORT8(8) MERGE16_FROM_8

  // ---- cross-lane merges 16->32->64->128 ----
  CROSS_REV(1, 1)                          INLANE16
  CROSS_REV(3, 2) CROSS(1, 1)              INLANE16
  CROSS_REV(7, 4) CROSS(2, 2) CROSS(1, 1)  INLANE16

  // ---- dt (last sample of ray gets dt = 0) ----
  const float nxt = __shfl(v[0], (lane + 1) & 63);
  float dt[16];
#pragma unroll
  for (int r = 0; r < 15; ++r) dt[r] = v[r + 1] - v[r];
  dt[15] = (gl == 7) ? 0.0f : (nxt - v[15]);

  // ---- sigma * dt, in-lane inclusive prefix p[] ----
  const float4* sb = (const float4*)(sigma + (size_t)ray * 128 + gl * 16);
  float p[16];
  {
    float run = 0.f;
#pragma unroll
    for (int q = 0; q < 4; ++q) {
      const float4 a = sb[q];
      run += a.x * dt[4*q+0]; p[4*q+0] = run;
      run += a.y * dt[4*q+1]; p[4*q+1] = run;
      run += a.z * dt[4*q+2]; p[4*q+2] = run;
      run += a.w * dt[4*q+3]; p[4*q+3] = run;
    }
  }

  // ---- 8-lane exclusive scan of lane totals ----
  float s = p[15];
#pragma unroll
  for (int off = 1; off < 8; off <<= 1) {
    const float u = __shfl_up(s, off);
    if (gl >= off) s += u;
  }
  const float excl = s - p[15];  // sum of all sdt before this lane's samples

  // ---- weights: wi_i = exp(-cum_excl_i) - exp(-cum_incl_i) ----
  float wi[16];
  {
    float Eprev = __expf(-excl);
#pragma unroll
    for (int r = 0; r < 16; ++r) {
      const float Er = __expf(-(excl + p[r]));
      wi[r] = Eprev - Er;
      Eprev = Er;
    }
  }

  // ---- color / depth partials (c loaded here; short live range) ----
  float pr = 0.f, pg = 0.f, pb = 0.f, pd = 0.f;
  {
    const float4* cb = (const float4*)(c + (size_t)ray * 384 + gl * 48);
    float carr[48];
#pragma unroll
    for (int q = 0; q < 12; ++q) *(float4*)&carr[q * 4] = cb[q];
#pragma unroll
    for (int r = 0; r < 16; ++r) {
      pr += wi[r] * carr[3 * r + 0];
      pg += wi[r] * carr[3 * r + 1];
      pb += wi[r] * carr[3 * r + 2];
      pd += wi[r] * v[r];
    }
  }

  // ---- 8-lane butterfly reduction ----
#pragma unroll
  for (int m = 4; m >= 1; m >>= 1) {
    pr += __shfl_xor(pr, m);
    pg += __shfl_xor(pg, m);
    pb += __shfl_xor(pb, m);
    pd += __shfl_xor(pd, m);
  }

  // ---- stores: out = color [N*3] | depth [N] | wi [N*128] ----
  float* wo = out + (size_t)n_rays * 4 + (size_t)ray * 128 + gl * 16;
#pragma unroll
  for (int q = 0; q < 4; ++q)
    *(float4*)(wo + 4 * q) =
        make_float4(wi[4*q+0], wi[4*q+1], wi[4*q+2], wi[4*q+3]);
  if (gl == 0) {
    out[(size_t)ray * 3 + 0] = pr;
    out[(size_t)ray * 3 + 1] = pg;
    out[(size_t)ray * 3 + 2] = pb;
    out[(size_t)n_rays * 3 + ray] = pd;
  }
}

extern "C" void kernel_launch(void* const* d_in, const int* in_sizes, int n_in,
                              void* d_out, int out_size, void* d_ws, size_t ws_size,
                              hipStream_t stream) {
  const float* t     = (const float*)d_in[0];
  const float* sigma = (const float*)d_in[1];
  const float* c     = (const float*)d_in[2];
  float* out = (float*)d_out;
  const int n_rays = in_sizes[0] / 128;
  const int blocks = (n_rays + 31) / 32;   // 32 rays per 256-thread block
  nerf_render_kernel<<<blocks, 256, 0, stream>>>(t, sigma, c, out, n_rays);
}

// Round 6
// 33.133 us; speedup vs baseline: 1.5352x; 1.5352x over previous
//
#include <hip/hip_runtime.h>

// NeRF volume rendering. R5 = R1 structure (8 samples/lane, 16 lanes/ray,
// 4 rays/wave) with all cross-lane traffic moved from the DS pipe (shfl ->
// ds_swizzle/bpermute) to DPP (VALU lane permutes). Each ray = one 16-lane
// DPP row, so quad_perm / mirrors / row shifts cover every mask except
// xor4 (one pass, kept as __shfl_xor).

#define DPP_QUAD_XOR1   0xB1   // quad_perm [1,0,3,2]
#define DPP_QUAD_XOR2   0x4E   // quad_perm [2,3,0,1]
#define DPP_QUAD_XOR3   0x1B   // quad_perm [3,2,1,0]
#define DPP_HALF_MIRROR 0x141  // xor7 within 16-lane row
#define DPP_ROW_MIRROR  0x140  // xor15 within 16-lane row
#define DPP_SHR1        0x111  // lane i <- lane i-1 (0-fill)
#define DPP_SHR2        0x112
#define DPP_SHR4        0x114
#define DPP_SHR8        0x118
#define DPP_SHL1        0x101  // lane i <- lane i+1 (0-fill)
#define DPP_SHL2        0x102
#define DPP_SHL4        0x104
#define DPP_SHL8        0x108

template <int CTRL>
__device__ __forceinline__ float dppf(float x) {
  return __int_as_float(__builtin_amdgcn_update_dpp(
      0, __float_as_int(x), CTRL, 0xF, 0xF, true));
}

#define CEX(a,b) { float mn_=fminf(v[a],v[b]); v[b]=fmaxf(v[a],v[b]); v[a]=mn_; }

// first pass of merge S->2S via DPP: partner = reversed regs, lane xor mask
#define CROSS_REV_DPP(CTRL, lowbit) { \
  float w_[8]; \
  _Pragma("unroll") for (int r_=0;r_<8;++r_) w_[r_]=dppf<CTRL>(v[7-r_]); \
  const bool lo_ = (gl & (lowbit)) == 0; \
  _Pragma("unroll") for (int r_=0;r_<8;++r_) \
    v[r_] = lo_ ? fminf(v[r_],w_[r_]) : fmaxf(v[r_],w_[r_]); }

// uniform-ascending cross-lane CE pass via DPP
#define CROSS_DPP(CTRL, lowbit) { \
  float w_[8]; \
  _Pragma("unroll") for (int r_=0;r_<8;++r_) w_[r_]=dppf<CTRL>(v[r_]); \
  const bool lo_ = (gl & (lowbit)) == 0; \
  _Pragma("unroll") for (int r_=0;r_<8;++r_) \
    v[r_] = lo_ ? fminf(v[r_],w_[r_]) : fmaxf(v[r_],w_[r_]); }

// xor4 has no DPP control — keep the DS-pipe shuffle for this one pass
#define CROSS_SWZ(mask, lowbit) { \
  float w_[8]; \
  _Pragma("unroll") for (int r_=0;r_<8;++r_) w_[r_]=__shfl_xor(v[r_], (mask)); \
  const bool lo_ = (gl & (lowbit)) == 0; \
  _Pragma("unroll") for (int r_=0;r_<8;++r_) \
    v[r_] = lo_ ? fminf(v[r_],w_[r_]) : fmaxf(v[r_],w_[r_]); }

// in-lane ascending bitonic merge of 8 (strides 4,2,1)
#define INLANE8() { CEX(0,4) CEX(1,5) CEX(2,6) CEX(3,7) \
                    CEX(0,2) CEX(1,3) CEX(4,6) CEX(5,7) \
                    CEX(0,1) CEX(2,3) CEX(4,5) CEX(6,7) }

__global__ __launch_bounds__(256) void nerf_render_kernel(
    const float* __restrict__ t,
    const float* __restrict__ sigma,
    const float* __restrict__ c,
    float* __restrict__ out,
    int n_rays) {
  const int tid  = threadIdx.x;
  const int lane = tid & 63;
  const int gl   = lane & 15;               // lane within the 16-lane ray group
  const int ray  = blockIdx.x * 16 + (tid >> 4);
  if (ray >= n_rays) return;

  // ---- load t: 8 contiguous samples per lane ----
  const float4* tb = (const float4*)(t + (size_t)ray * 128 + gl * 8);
  float v[8];
  { float4 a = tb[0], b = tb[1];
    v[0]=a.x; v[1]=a.y; v[2]=a.z; v[3]=a.w;
    v[4]=b.x; v[5]=b.y; v[6]=b.z; v[7]=b.w; }

  // ---- in-lane Batcher odd-even mergesort of 8 (ascending, 19 CEs) ----
  CEX(0,1) CEX(2,3) CEX(4,5) CEX(6,7)
  CEX(0,2) CEX(1,3) CEX(4,6) CEX(5,7)
  CEX(1,2) CEX(5,6)
  CEX(0,4) CEX(1,5) CEX(2,6) CEX(3,7)
  CEX(2,4) CEX(3,5)
  CEX(1,2) CEX(3,4) CEX(5,6)

  // ---- merges 8->16 / 16->32 / 32->64 / 64->128 (DPP cross-lane) ----
  CROSS_REV_DPP(DPP_QUAD_XOR1, 1)  INLANE8()
  CROSS_REV_DPP(DPP_QUAD_XOR3, 2)  CROSS_DPP(DPP_QUAD_XOR1, 1)  INLANE8()
  CROSS_REV_DPP(DPP_HALF_MIRROR, 4) CROSS_DPP(DPP_QUAD_XOR2, 2)
    CROSS_DPP(DPP_QUAD_XOR1, 1)    INLANE8()
  CROSS_REV_DPP(DPP_ROW_MIRROR, 8)  CROSS_SWZ(4, 4)
    CROSS_DPP(DPP_QUAD_XOR2, 2)    CROSS_DPP(DPP_QUAD_XOR1, 1)  INLANE8()

  // ---- dt (last sample of ray gets dt = 0) ----
  const float nxt = dppf<DPP_SHL1>(v[0]);   // row-scoped: no cross-ray wrap
  float dt[8];
#pragma unroll
  for (int r = 0; r < 7; ++r) dt[r] = v[r + 1] - v[r];
  dt[7] = (gl == 15) ? 0.0f : (nxt - v[7]);

  // ---- sigma * dt ----
  const float4* sb = (const float4*)(sigma + (size_t)ray * 128 + gl * 8);
  float sdt[8];
  { float4 a = sb[0], b = sb[1];
    sdt[0]=a.x*dt[0]; sdt[1]=a.y*dt[1]; sdt[2]=a.z*dt[2]; sdt[3]=a.w*dt[3];
    sdt[4]=b.x*dt[4]; sdt[5]=b.y*dt[5]; sdt[6]=b.z*dt[6]; sdt[7]=b.w*dt[7]; }

  // ---- prefix sums: in-lane inclusive, then 16-lane scan via row_shr ----
  float p[8];
  p[0] = sdt[0];
#pragma unroll
  for (int r = 1; r < 8; ++r) p[r] = p[r - 1] + sdt[r];
  float s = p[7];
  s += dppf<DPP_SHR1>(s);   // zero-fill == identity for add
  s += dppf<DPP_SHR2>(s);
  s += dppf<DPP_SHR4>(s);
  s += dppf<DPP_SHR8>(s);
  const float excl = s - p[7];   // sum of all sdt before this lane's samples

  // ---- weights: wi_i = exp(-cum_excl_i) - exp(-cum_incl_i) ----
  float wi[8];
  float Eprev = __expf(-excl);
#pragma unroll
  for (int r = 0; r < 8; ++r) {
    const float Er = __expf(-(excl + p[r]));
    wi[r] = Eprev - Er;
    Eprev = Er;
  }

  // ---- color / depth partials ----
  float carr[24];
  { const float4* cb = (const float4*)(c + (size_t)ray * 384 + gl * 24);
#pragma unroll
    for (int q = 0; q < 6; ++q) *(float4*)&carr[q * 4] = cb[q]; }
  float pr = 0.f, pg = 0.f, pb = 0.f, pd = 0.f;
#pragma unroll
  for (int r = 0; r < 8; ++r) {
    pr += wi[r] * carr[3 * r + 0];
    pg += wi[r] * carr[3 * r + 1];
    pb += wi[r] * carr[3 * r + 2];
    pd += wi[r] * v[r];
  }

  // ---- 16-lane down-shift reduction (result needed only at gl==0) ----
  pr += dppf<DPP_SHL8>(pr); pg += dppf<DPP_SHL8>(pg);
  pb += dppf<DPP_SHL8>(pb); pd += dppf<DPP_SHL8>(pd);
  pr += dppf<DPP_SHL4>(pr); pg += dppf<DPP_SHL4>(pg);
  pb += dppf<DPP_SHL4>(pb); pd += dppf<DPP_SHL4>(pd);
  pr += dppf<DPP_SHL2>(pr); pg += dppf<DPP_SHL2>(pg);
  pb += dppf<DPP_SHL2>(pb); pd += dppf<DPP_SHL2>(pd);
  pr += dppf<DPP_SHL1>(pr); pg += dppf<DPP_SHL1>(pg);
  pb += dppf<DPP_SHL1>(pb); pd += dppf<DPP_SHL1>(pd);

  // ---- stores: out = color [N*3] | depth [N] | wi [N*128] ----
  float* wo = out + (size_t)n_rays * 4 + (size_t)ray * 128 + gl * 8;
  *(float4*)(wo)     = make_float4(wi[0], wi[1], wi[2], wi[3]);
  *(float4*)(wo + 4) = make_float4(wi[4], wi[5], wi[6], wi[7]);
  if (gl == 0) {
    out[(size_t)ray * 3 + 0] = pr;
    out[(size_t)ray * 3 + 1] = pg;
    out[(size_t)ray * 3 + 2] = pb;
    out[(size_t)n_rays * 3 + ray] = pd;
  }
}

extern "C" void kernel_launch(void* const* d_in, const int* in_sizes, int n_in,
                              void* d_out, int out_size, void* d_ws, size_t ws_size,
                              hipStream_t stream) {
  const float* t     = (const float*)d_in[0];
  const float* sigma = (const float*)d_in[1];
  const float* c     = (const float*)d_in[2];
  float* out = (float*)d_out;
  const int n_rays = in_sizes[0] / 128;
  const int blocks = (n_rays + 15) / 16;   // 16 rays per 256-thread block
  nerf_render_kernel<<<blocks, 256, 0, stream>>>(t, sigma, c, out, n_rays);
}